// Round 1
// baseline (345.842 us; speedup 1.0000x reference)
//
#include <hip/hip_runtime.h>
#include <cstdint>
#include <cstddef>

#define B_ROWS 16384
#define D_COLS 2048
#define NCLS   1000

// ---------------- Threefry-2x32 (JAX-compatible), host+device ----------------
__host__ __device__ __forceinline__ uint32_t rotl32(uint32_t v, int r) {
    return (v << r) | (v >> (32 - r));
}

__host__ __device__ inline void tf2x32(uint32_t k0, uint32_t k1,
                                       uint32_t x0, uint32_t x1,
                                       uint32_t& o0, uint32_t& o1) {
    uint32_t ks0 = k0, ks1 = k1, ks2 = k0 ^ k1 ^ 0x1BD11BDAu;
    x0 += ks0; x1 += ks1;
    // group 1 (rotations A: 13,15,26,6)
    x0 += x1; x1 = rotl32(x1, 13); x1 ^= x0;
    x0 += x1; x1 = rotl32(x1, 15); x1 ^= x0;
    x0 += x1; x1 = rotl32(x1, 26); x1 ^= x0;
    x0 += x1; x1 = rotl32(x1, 6);  x1 ^= x0;
    x0 += ks1; x1 += ks2 + 1u;
    // group 2 (rotations B: 17,29,16,24)
    x0 += x1; x1 = rotl32(x1, 17); x1 ^= x0;
    x0 += x1; x1 = rotl32(x1, 29); x1 ^= x0;
    x0 += x1; x1 = rotl32(x1, 16); x1 ^= x0;
    x0 += x1; x1 = rotl32(x1, 24); x1 ^= x0;
    x0 += ks2; x1 += ks0 + 2u;
    // group 3 (A)
    x0 += x1; x1 = rotl32(x1, 13); x1 ^= x0;
    x0 += x1; x1 = rotl32(x1, 15); x1 ^= x0;
    x0 += x1; x1 = rotl32(x1, 26); x1 ^= x0;
    x0 += x1; x1 = rotl32(x1, 6);  x1 ^= x0;
    x0 += ks0; x1 += ks1 + 3u;
    // group 4 (B)
    x0 += x1; x1 = rotl32(x1, 17); x1 ^= x0;
    x0 += x1; x1 = rotl32(x1, 29); x1 ^= x0;
    x0 += x1; x1 = rotl32(x1, 16); x1 ^= x0;
    x0 += x1; x1 = rotl32(x1, 24); x1 ^= x0;
    x0 += ks1; x1 += ks2 + 4u;
    // group 5 (A)
    x0 += x1; x1 = rotl32(x1, 13); x1 ^= x0;
    x0 += x1; x1 = rotl32(x1, 15); x1 ^= x0;
    x0 += x1; x1 = rotl32(x1, 26); x1 ^= x0;
    x0 += x1; x1 = rotl32(x1, 6);  x1 ^= x0;
    x0 += ks2; x1 += ks0 + 5u;
    o0 = x0; o1 = x1;
}

// XLA ErfInv (f32, Giles approximation)
__device__ __forceinline__ float erfinv_f(float x) {
    float w = -log1pf(-x * x);
    float p;
    if (w < 5.0f) {
        w -= 2.5f;
        p = 2.81022636e-08f;
        p = fmaf(p, w, 3.43273939e-07f);
        p = fmaf(p, w, -3.5233877e-06f);
        p = fmaf(p, w, -4.39150654e-06f);
        p = fmaf(p, w, 0.00021858087f);
        p = fmaf(p, w, -0.00125372503f);
        p = fmaf(p, w, -0.00417768164f);
        p = fmaf(p, w, 0.246640727f);
        p = fmaf(p, w, 1.50140941f);
    } else {
        w = sqrtf(w) - 3.0f;
        p = -0.000200214257f;
        p = fmaf(p, w, 0.000100950558f);
        p = fmaf(p, w, 0.00134934322f);
        p = fmaf(p, w, -0.00367342844f);
        p = fmaf(p, w, 0.00573950773f);
        p = fmaf(p, w, -0.0076224613f);
        p = fmaf(p, w, 0.00943887047f);
        p = fmaf(p, w, 1.00167406f);
        p = fmaf(p, w, 2.83297682f);
    }
    return p * x;
}

// ------------------------------- kernels -------------------------------------

// y-histogram + sort-key generation for both shuffle rounds.
// Partitionable random_bits(32): bits[i] = o0 ^ o1 of enc(subkey, (0, i)).
// Composed stable-sort key: (bits << 14) | i  (index breaks ties == stable sort).
__global__ void k_bits_hist(const int* __restrict__ y, int* __restrict__ cnt,
                            unsigned long long* __restrict__ kA,
                            unsigned long long* __restrict__ kB,
                            uint32_t s1_0, uint32_t s1_1,
                            uint32_t s2_0, uint32_t s2_1) {
    int i = blockIdx.x * 256 + threadIdx.x;
    atomicAdd(&cnt[y[i]], 1);
    uint32_t a, b;
    tf2x32(s1_0, s1_1, 0u, (uint32_t)i, a, b);
    kA[i] = ((unsigned long long)(a ^ b) << 14) | (unsigned)i;
    tf2x32(s2_0, s2_1, 0u, (uint32_t)i, a, b);
    kB[i] = ((unsigned long long)(a ^ b) << 14) | (unsigned)i;
}

// exclusive prefix sum of cnt[1000] -> rowstart[1000]
__global__ void k_prefix(const int* __restrict__ cnt, int* __restrict__ rowstart) {
    __shared__ int sm[1024];
    int t = threadIdx.x;
    int v = (t < NCLS) ? cnt[t] : 0;
    sm[t] = v;
    for (int off = 1; off < 1024; off <<= 1) {
        __syncthreads();
        int u = (t >= off) ? sm[t - off] : 0;
        __syncthreads();
        sm[t] += u;
    }
    if (t < NCLS) rowstart[t] = sm[t] - v;
}

// bucket row indices by class
__global__ void k_scatter_rows(const int* __restrict__ y, const int* __restrict__ rowstart,
                               int* __restrict__ rowpos, int* __restrict__ rowlist) {
    int i = blockIdx.x * 256 + threadIdx.x;
    int c = y[i];
    int p = atomicAdd(&rowpos[c], 1);
    rowlist[rowstart[c] + p] = i;
}

// per-class sum and sum-of-squares; one block per class, no atomics
__global__ void __launch_bounds__(256) k_class_sums(
        const float* __restrict__ x, const int* __restrict__ rowlist,
        const int* __restrict__ rowstart, const int* __restrict__ cnt,
        float* __restrict__ s, float* __restrict__ sq) {
    int c = blockIdx.x, t = threadIdx.x;
    int start = rowstart[c], n = cnt[c];
    float s0x=0,s0y=0,s0z=0,s0w=0, s1x=0,s1y=0,s1z=0,s1w=0;
    float q0x=0,q0y=0,q0z=0,q0w=0, q1x=0,q1y=0,q1z=0,q1w=0;
    const float4* xb = (const float4*)x;
    for (int r = 0; r < n; r++) {
        int row = rowlist[start + r];
        const float4* xr = xb + (size_t)row * (D_COLS / 4);
        float4 a = xr[t];
        float4 b = xr[t + 256];
        s0x += a.x; s0y += a.y; s0z += a.z; s0w += a.w;
        q0x = fmaf(a.x, a.x, q0x); q0y = fmaf(a.y, a.y, q0y);
        q0z = fmaf(a.z, a.z, q0z); q0w = fmaf(a.w, a.w, q0w);
        s1x += b.x; s1y += b.y; s1z += b.z; s1w += b.w;
        q1x = fmaf(b.x, b.x, q1x); q1y = fmaf(b.y, b.y, q1y);
        q1z = fmaf(b.z, b.z, q1z); q1w = fmaf(b.w, b.w, q1w);
    }
    float4* s4 = (float4*)(s + (size_t)c * D_COLS);
    float4* q4 = (float4*)(sq + (size_t)c * D_COLS);
    s4[t]       = make_float4(s0x, s0y, s0z, s0w);
    s4[t + 256] = make_float4(s1x, s1y, s1z, s1w);
    q4[t]       = make_float4(q0x, q0y, q0z, q0w);
    q4[t + 256] = make_float4(q1x, q1y, q1z, q1w);
}

// class_noise[c][d] = mean + std * (sqrt2 * erfinv(u)),  u from threefry bits
__global__ void k_noise(const float* __restrict__ s, const float* __restrict__ sq,
                        const int* __restrict__ cnt, float* __restrict__ noise,
                        uint32_t nk0, uint32_t nk1) {
    int n = blockIdx.x * 256 + threadIdx.x;       // < 2048000
    uint32_t b1, b2;
    tf2x32(nk0, nk1, 0u, (uint32_t)n, b1, b2);
    uint32_t bits = b1 ^ b2;
    float f = __uint_as_float((bits >> 9) | 0x3f800000u) - 1.0f;
    const float LO = -0.99999994f;                 // nextafter(-1,0) in f32
    float u = fmaxf(LO, fmaf(f, 2.0f, LO));        // (hi-lo) rounds to 2.0f
    float nr = 1.41421356f * erfinv_f(u);
    int c = n >> 11;
    float cf = (float)cnt[c];
    float m = s[n] / cf;
    float var = (sq[n] - cf * m * m) / (cf - 1.0f);
    float sd = sqrtf(fmaxf(var, 0.0f));
    noise[n] = fmaf(sd, nr, m);
}

// rank of each element under stable ascending sort, both rounds in one kernel.
// grid (64 i-tiles, 16 j-tiles); j-tile (1024 keys each round) staged in LDS.
__global__ void __launch_bounds__(256) k_rank12(
        const unsigned long long* __restrict__ kA,
        const unsigned long long* __restrict__ kB,
        int* __restrict__ rankA, int* __restrict__ rankB) {
    __shared__ unsigned long long sA[1024];
    __shared__ unsigned long long sB[1024];
    int t = threadIdx.x;
    int jbase = blockIdx.y * 1024;
    for (int k = t; k < 1024; k += 256) {
        sA[k] = kA[jbase + k];
        sB[k] = kB[jbase + k];
    }
    __syncthreads();
    int i = blockIdx.x * 256 + t;
    unsigned long long a = kA[i], b = kB[i];
    int ca = 0, cb = 0;
#pragma unroll 8
    for (int j = 0; j < 1024; j++) {
        ca += (sA[j] < a);
        cb += (sB[j] < b);
    }
    atomicAdd(&rankA[i], ca);
    atomicAdd(&rankB[i], cb);
}

// round 1 scatter: x1[rank1[i]] = i   (values were arange)
__global__ void k_scatter1(const int* __restrict__ rank1, int* __restrict__ x1) {
    int i = blockIdx.x * 256 + threadIdx.x;
    x1[rank1[i]] = i;
}

// round 2 scatter fused with gather: newY[rank2[i]] = y[x1[i]]; also f32 tail of d_out
__global__ void k_scatter2(const int* __restrict__ y, const int* __restrict__ x1,
                           const int* __restrict__ rank2, int* __restrict__ newY,
                           float* __restrict__ outTail) {
    int i = blockIdx.x * 256 + threadIdx.x;
    int v = y[x1[i]];
    int j = rank2[i];
    newY[j] = v;
    outTail[j] = (float)v;
}

// out[b][d] = 0.9*x[b][d] + 0.1*noise[newY[b]][d]
__global__ void __launch_bounds__(256) k_final(
        const float* __restrict__ x, const float* __restrict__ noise,
        const int* __restrict__ newY, float* __restrict__ out) {
    int b = blockIdx.x, t = threadIdx.x;
    int ny = newY[b];
    const float4* xr = (const float4*)x + (size_t)b * (D_COLS / 4);
    const float4* nr = (const float4*)noise + (size_t)ny * (D_COLS / 4);
    float4* orow = (float4*)out + (size_t)b * (D_COLS / 4);
    float4 xa = xr[t], na = nr[t];
    float4 o;
    o.x = fmaf(0.1f, na.x, 0.9f * xa.x);
    o.y = fmaf(0.1f, na.y, 0.9f * xa.y);
    o.z = fmaf(0.1f, na.z, 0.9f * xa.z);
    o.w = fmaf(0.1f, na.w, 0.9f * xa.w);
    orow[t] = o;
    xa = xr[t + 256]; na = nr[t + 256];
    o.x = fmaf(0.1f, na.x, 0.9f * xa.x);
    o.y = fmaf(0.1f, na.y, 0.9f * xa.y);
    o.z = fmaf(0.1f, na.z, 0.9f * xa.z);
    o.w = fmaf(0.1f, na.w, 0.9f * xa.w);
    orow[t + 256] = o;
}

// ------------------------------- launcher ------------------------------------
extern "C" void kernel_launch(void* const* d_in, const int* in_sizes, int n_in,
                              void* d_out, int out_size, void* d_ws, size_t ws_size,
                              hipStream_t stream) {
    const float* x = (const float*)d_in[0];
    const int* y = (const int*)d_in[1];
    float* out = (float*)d_out;
    float* outTail = out + (size_t)B_ROWS * D_COLS;

    char* ws = (char*)d_ws;
    float* s     = (float*)(ws);                      // 1000*2048 f32 = 8,192,000 B
    float* sq    = (float*)(ws + 8192000);            // 8,192,000 B
    float* noise = (float*)(ws + 16384000);           // 8,192,000 B
    unsigned long long* kA = (unsigned long long*)(ws + 24576000);  // 131,072 B
    unsigned long long* kB = (unsigned long long*)(ws + 24707072);  // 131,072 B
    int* ints = (int*)(ws + 24838144);
    int* cnt      = ints;           // 1000
    int* rowpos   = ints + 1000;    // 1000
    int* rank1    = ints + 2000;    // 16384
    int* rank2    = ints + 18384;   // 16384
    int* rowstart = ints + 34768;   // 1000
    int* rowlist  = ints + 35768;   // 16384
    int* x1       = ints + 52152;   // 16384
    int* newY     = ints + 68536;   // 16384

    // zero the accumulated regions (cnt, rowpos, rank1, rank2)
    hipMemsetAsync(cnt, 0, 34768 * sizeof(int), stream);

    // Host-side key derivation (jax.random.key(42), partitionable/foldlike split):
    //   split(k) children: child_i = enc(k, (0, i));  nk = child0, pk = child1
    //   shuffle round r: key,sub = split(key) -> sub_r = child1
    uint32_t nk0, nk1, pk0, pk1, pn0, pn1, s1_0, s1_1, s2_0, s2_1;
    tf2x32(0u, 42u, 0u, 0u, nk0, nk1);   // nk (noise key)
    tf2x32(0u, 42u, 0u, 1u, pk0, pk1);   // pk (perm key)
    tf2x32(pk0, pk1, 0u, 0u, pn0, pn1);  // pk after round-1 split
    tf2x32(pk0, pk1, 0u, 1u, s1_0, s1_1); // round-1 subkey
    tf2x32(pn0, pn1, 0u, 1u, s2_0, s2_1); // round-2 subkey

    k_bits_hist<<<64, 256, 0, stream>>>(y, cnt, kA, kB, s1_0, s1_1, s2_0, s2_1);
    k_prefix<<<1, 1024, 0, stream>>>(cnt, rowstart);
    k_scatter_rows<<<64, 256, 0, stream>>>(y, rowstart, rowpos, rowlist);
    k_class_sums<<<NCLS, 256, 0, stream>>>(x, rowlist, rowstart, cnt, s, sq);
    k_noise<<<8000, 256, 0, stream>>>(s, sq, cnt, noise, nk0, nk1);
    k_rank12<<<dim3(64, 16), 256, 0, stream>>>(kA, kB, rank1, rank2);
    k_scatter1<<<64, 256, 0, stream>>>(rank1, x1);
    k_scatter2<<<64, 256, 0, stream>>>(y, x1, rank2, newY, outTail);
    k_final<<<16384, 256, 0, stream>>>(x, noise, newY, out);
}